// Round 18
// baseline (19611.369 us; speedup 1.0000x reference)
//
#include <hip/hip_runtime.h>
#include <math.h>

#define L_SEQ 8192
#define I_DIM 256
#define H_DIM 2048
#define NWG0  64          // layer-0: 64 WGs x 32 rows (col-block: 4 rows/wave)
#define NWG1  128         // layer-1: 128 WGs x 16 rows (col-block: 2 rows/wave)
#define NWG   (NWG0 + NWG1)
#define TPB   512
#define RD    16          // h ring depth
#define RM    (RD - 1)
#define TLAG  11          // L0 throttle lag (checked every 4th step)

// ws (bytes): [0] runctr | [256..1024) bslots | [4096) h0 ring 16*2048 f32
//             | [4096+128K) h1 ring 16*2048 f32
//
// Base = round-17 (best: 18.9 ms): tagged dataflow (value = h + ctr(step),
// ctr = 4+8*((step>>4)&1), ring 16, |v-ctr|<=1 valid), per-run slot re-init,
// start barrier on monotone runctr, throttle lag 11 every 4th step, packed
// publishes, s_sleep backoff, col-block compute (lane owns 32 cols, padded
// LDS pos j+(j>>3), 6-level shfl reduce, lane0 packed publish), L1 h0
// prefetch (stale-read), L0 x-trim. r13 (early h1 poll), r14 (128 L0 WGs),
// r16 (cross-sync conditional pf asm -- CRASHED) are excluded.
//
// Round-18 diff: HALF-WG WIDE-POLL on both fresh detects. Threads 0..255
// poll TWO adjacent granules each (pipelined dwordx4 pair, r13's poll8) and
// stage both; threads 256..511 skip to the sync (L0: waves 4-5 run the
// throttle there, overlapped). Per-vector poll requests 512->256 per WG,
// straggler set halves, detect-phase LLC pressure halves. L1's pfA wait is
// a uniform vmcnt(0) tie (no divergent vmcnt bookkeeping).

typedef float f32x4 __attribute__((ext_vector_type(4)));
typedef float f32x2 __attribute__((ext_vector_type(2)));

__device__ __forceinline__ void cstore1(float* p, float v) {
  asm volatile("global_store_dword %0, %1, off sc0 sc1" :: "v"(p), "v"(v) : "memory");
}
__device__ __forceinline__ void cstore2f(float* p, float a, float b) {
  f32x2 v; v.x = a; v.y = b;
  asm volatile("global_store_dwordx2 %0, %1, off sc0 sc1" :: "v"(p), "v"(v) : "memory");
}
__device__ __forceinline__ void cstore4f(float* p, float a, float b, float c, float d) {
  f32x4 v; v.x = a; v.y = b; v.z = c; v.w = d;
  asm volatile("global_store_dwordx4 %0, %1, off sc0 sc1" :: "v"(p), "v"(v) : "memory");
}
__device__ __forceinline__ void cstoreu(unsigned* p, unsigned v) {
  asm volatile("global_store_dword %0, %1, off sc0 sc1" :: "v"(p), "v"(v) : "memory");
}
__device__ __forceinline__ float cload1(const float* p) {
  float v;
  asm volatile("global_load_dword %0, %1, off sc0 sc1\n\ts_waitcnt vmcnt(0)"
               : "=v"(v) : "v"(p) : "memory");
  return v;
}
__device__ __forceinline__ unsigned cloadu(const unsigned* p) {
  unsigned v;
  asm volatile("global_load_dword %0, %1, off sc0 sc1\n\ts_waitcnt vmcnt(0)"
               : "=v"(v) : "v"(p) : "memory");
  return v;
}
__device__ __forceinline__ float4 cload4(const float* p) {
  float4 v;
  asm volatile("global_load_dwordx4 %0, %1, off sc0 sc1\n\ts_waitcnt vmcnt(0)"
               : "=v"(v) : "v"(p) : "memory");
  return v;
}
__device__ __forceinline__ void cload4x2(const float* p0, const float* p1, float4& a, float4& b) {
  asm volatile("global_load_dwordx4 %0, %2, off sc0 sc1\n\t"
               "global_load_dwordx4 %1, %3, off sc0 sc1\n\t"
               "s_waitcnt vmcnt(0)"
               : "=&v"(a), "=&v"(b) : "v"(p0), "v"(p1) : "memory");
}
__device__ __forceinline__ float4 ld4(const float* p) {   // weight load, opaque
  float4 v;
  asm volatile("global_load_dwordx4 %0, %1, off\n\ts_waitcnt vmcnt(0)"
               : "=v"(v) : "v"(p) : "memory");
  return v;
}
// prefetch: issue WITHOUT waitcnt; drained by a later vmcnt(0)
__device__ __forceinline__ void pf_issue(f32x4& v, const float* p) {
  asm volatile("global_load_dwordx4 %0, %1, off sc0 sc1" : "=&v"(v) : "v"(p) : "memory");
}
__device__ __forceinline__ void pf_wait0(f32x4& v) {   // uniform full drain
  asm volatile("s_waitcnt vmcnt(0)" : "+v"(v) :: "memory");
  __builtin_amdgcn_sched_barrier(0);
}
__device__ __forceinline__ float tagc(int step) {
  return 4.f + 8.f * (float)((step >> 4) & 1);
}
__device__ __forceinline__ bool ok4(float4 v, float c) {
  return __builtin_fabsf(v.x - c) <= 1.f && __builtin_fabsf(v.y - c) <= 1.f &&
         __builtin_fabsf(v.z - c) <= 1.f && __builtin_fabsf(v.w - c) <= 1.f;
}
__device__ __forceinline__ bool ok4x(f32x4 v, float c) {
  return __builtin_fabsf(v.x - c) <= 1.f && __builtin_fabsf(v.y - c) <= 1.f &&
         __builtin_fabsf(v.z - c) <= 1.f && __builtin_fabsf(v.w - c) <= 1.f;
}
__device__ __forceinline__ float4 poll4(const float* p, float c) {
  float4 v = cload4(p);
  while (!ok4(v, c)) { __builtin_amdgcn_s_sleep(1); v = cload4(p); }
  return make_float4(v.x - c, v.y - c, v.z - c, v.w - c);
}
// two adjacent granules (32B), same tag: pipelined pair, re-issue on any-stale
__device__ __forceinline__ void poll8(const float* p, float c, float4& a, float4& b) {
  float4 u, v;
  cload4x2(p, p + 4, u, v);
  while (!(ok4(u, c) && ok4(v, c))) {
    __builtin_amdgcn_s_sleep(1);
    cload4x2(p, p + 4, u, v);
  }
  a = make_float4(u.x - c, u.y - c, u.z - c, u.w - c);
  b = make_float4(v.x - c, v.y - c, v.z - c, v.w - c);
}
// validate a prefetched granule; fall back to backoff-poll if stale
__device__ __forceinline__ float4 pf_finish(f32x4 pf, const float* p, float c) {
  if (!ok4x(pf, c)) {
    do {
      __builtin_amdgcn_s_sleep(1);
      float4 r = cload4(p);
      pf.x = r.x; pf.y = r.y; pf.z = r.z; pf.w = r.w;
    } while (!ok4x(pf, c));
  }
  return make_float4(pf.x - c, pf.y - c, pf.z - c, pf.w - c);
}
__device__ __forceinline__ float dot4(float4 a, float4 b) {
  return a.x * b.x + a.y * b.y + a.z * b.z + a.w * b.w;
}
__device__ __forceinline__ float tanh_fast(float v) {   // exact identity
  float e = __expf(2.f * v);
  return 1.f - 2.f / (e + 1.f);
}
__device__ __forceinline__ void start_barrier(unsigned* bslots, int wg, int tid, unsigned value) {
  __syncthreads();
  if (tid == 0) cstoreu(&bslots[wg], value);
  if (tid < NWG) {
    while ((int)(cloadu(&bslots[tid]) - value) < 0) __builtin_amdgcn_s_sleep(1);
  }
  __syncthreads();
}

__global__ __launch_bounds__(TPB, 2)
void rnn2_widepoll(const float* __restrict__ x,
                   const float* __restrict__ Wih0, const float* __restrict__ Whh0,
                   const float* __restrict__ bih0, const float* __restrict__ bhh0,
                   const float* __restrict__ Wih1, const float* __restrict__ Whh1,
                   const float* __restrict__ bih1, const float* __restrict__ bhh1,
                   const float* __restrict__ Wfc,  const float* __restrict__ bfc,
                   float* __restrict__ out,
                   unsigned* __restrict__ runctr, unsigned* __restrict__ bslots,
                   float* __restrict__ h0s, float* __restrict__ h1s)
{
  const int wg   = blockIdx.x;
  const int tid  = threadIdx.x;
  const int lane = tid & 63;
  const int wv   = tid >> 6;
  __shared__ float4 lds4[2][1152];   // padded: [0..576) h0, [576..1152) h1

  const unsigned runbase = cloadu(runctr);

  if (wg < NWG0) {
    // ---- layer 0: wave wv owns rows r0..r0+3; lane owns cols [32l, 32l+32) ----
    const int r0 = wg * 32 + wv * 4;
    float4 whhr[32];   // [j*8+k]: row r0+j, col f4 k of the lane's 8
    float4 wihr[4];    // [j]: row r0+j, x cols [4l, 4l+4)
    {
      #pragma unroll
      for (int j = 0; j < 4; ++j) {
        const float* wr2 = Whh0 + (size_t)(r0 + j) * H_DIM + (lane << 5);
        #pragma unroll
        for (int k = 0; k < 8; ++k) whhr[j * 8 + k] = ld4(wr2 + (k << 2));
        wihr[j] = ld4(Wih0 + (size_t)(r0 + j) * I_DIM + (lane << 2));
      }
    }
    const float bs0 = bih0[r0] + bhh0[r0];
    const float bs1 = bih0[r0 + 1] + bhh0[r0 + 1];
    const float bs2 = bih0[r0 + 2] + bhh0[r0 + 2];
    const float bs3 = bih0[r0 + 3] + bhh0[r0 + 3];

    {   // re-init all 16 ring slots of owned rows: slot0 = tagged h0_0 (=4.0)
      int sl = tid >> 5; int r = wg * 32 + (tid & 31);
      cstore1(&h0s[sl * H_DIM + r], (sl == 0) ? 4.f : 0.f);
    }
    start_barrier(bslots, wg, tid, runbase + 1);

    // x-partials for s=1 (row 0 of x; lane's 4 cols)
    float xp0, xp1, xp2, xp3;
    {
      float4 xv = ((const float4*)x)[lane];
      xp0 = dot4(wihr[0], xv); xp1 = dot4(wihr[1], xv);
      xp2 = dot4(wihr[2], xv); xp3 = dot4(wihr[3], xv);
    }

    for (int s = 1; s <= L_SEQ; ++s) {
      const int P = s & 1;
      const float c = tagc(s - 1);
      if (tid < 256) {
        // wide-poll: two adjacent granules per thread (fan-in halved)
        float4 a, b;
        poll8(h0s + ((s - 1) & RM) * H_DIM + (tid << 3), c, a, b);
        const int j0 = 2 * tid, j1 = 2 * tid + 1;
        lds4[P][j0 + (j0 >> 3)] = a;
        lds4[P][j1 + (j1 >> 3)] = b;
      } else if (tid < 384) {
        // throttle on the idle half (every 4th step, fully overlapped)
        if ((s & 3) == 0 && s >= 12) {
          const float tc = tagc(s - TLAG);
          const float* tp = h1s + ((s - TLAG) & RM) * H_DIM + ((tid - 256) << 4);
          while (__builtin_fabsf(cload1(tp) - tc) > 1.f) __builtin_amdgcn_s_sleep(1);
        }
      }
      __syncthreads();
      float p0 = xp0, p1 = xp1, p2 = xp2, p3 = xp3;
      #pragma unroll
      for (int k = 0; k < 8; ++k) {      // lane's 8 f4 of h0_{s-1}, padded layout
        float4 h = lds4[P][9 * lane + k];
        p0 += dot4(whhr[k], h);
        p1 += dot4(whhr[8 + k], h);
        p2 += dot4(whhr[16 + k], h);
        p3 += dot4(whhr[24 + k], h);
      }
      #pragma unroll
      for (int m = 1; m < 64; m <<= 1) { // 64-lane reduce, 4 parallel chains
        p0 += __shfl_xor(p0, m); p1 += __shfl_xor(p1, m);
        p2 += __shfl_xor(p2, m); p3 += __shfl_xor(p3, m);
      }
      if (lane == 0) {                   // lane0 holds all 4 rows: packed publish
        const float ct = tagc(s);
        cstore4f(h0s + (s & RM) * H_DIM + r0,
                 tanh_fast(p0 + bs0) + ct, tanh_fast(p1 + bs1) + ct,
                 tanh_fast(p2 + bs2) + ct, tanh_fast(p3 + bs3) + ct);
      }
      if (s < L_SEQ) {                   // x-partials for s+1, off the serial path
        float4 xv = ((const float4*)x)[s * 64 + lane];
        xp0 = dot4(wihr[0], xv); xp1 = dot4(wihr[1], xv);
        xp2 = dot4(wihr[2], xv); xp3 = dot4(wihr[3], xv);
      }
    }

    if (wg == 0) {
      // FC: sigmoid(h1_8192 . Wfc + bfc); slot 8192&15 = 0, ctr 4.
      // Last throttle (s=8192) gave L1 >= 8181 => slot 0 holds 8176 (tag 1,
      // rejected) or 8192 (tag 0, accepted); init value long overwritten.
      float4 hv = poll4(h1s + (tid << 2), tagc(L_SEQ));
      float4 wf = ((const float4*)Wfc)[tid];
      float pz = dot4(hv, wf);
      #pragma unroll
      for (int m = 1; m < 64; m <<= 1) pz += __shfl_xor(pz, m);
      float* red = (float*)&lds4[0][0];
      __syncthreads();
      if ((tid & 63) == 0) red[wv] = pz;
      __syncthreads();
      if (tid == 0) {
        float z = bfc[0];
        #pragma unroll
        for (int w = 0; w < 8; ++w) z += red[w];
        out[0] = 1.f / (1.f + __expf(-z));
        cstoreu(runctr, runbase + 1);
      }
    }
  } else {
    // ---- layer 1: wave wv owns rows r0, r0+1; lane owns cols [32l, 32l+32) ----
    const int wgl = wg - NWG0;
    const int r0  = wgl * 16 + wv * 2;
    float4 wihr[16], whhr[16];   // [j*8+k], j in {0,1}
    {
      #pragma unroll
      for (int j = 0; j < 2; ++j) {
        const float* wr = Wih1 + (size_t)(r0 + j) * H_DIM + (lane << 5);
        #pragma unroll
        for (int k = 0; k < 8; ++k) wihr[j * 8 + k] = ld4(wr + (k << 2));
        const float* wr2 = Whh1 + (size_t)(r0 + j) * H_DIM + (lane << 5);
        #pragma unroll
        for (int k = 0; k < 8; ++k) whhr[j * 8 + k] = ld4(wr2 + (k << 2));
      }
    }
    const float ba = bih1[r0] + bhh1[r0];
    const float bb = bih1[r0 + 1] + bhh1[r0 + 1];

    if (tid < 256) {   // re-init all 16 ring slots of owned rows
      int sl = tid >> 4; int r = wgl * 16 + (tid & 15);
      cstore1(&h1s[sl * H_DIM + r], (sl == 0) ? 4.f : 0.f);
    }
    start_barrier(bslots, wg, tid, runbase + 1);

    // prologue: issue prefetch of h0_1 (validated by uniform vmcnt(0) at t=1)
    f32x4 pfA;
    pf_issue(pfA, h0s + (1 & RM) * H_DIM + (tid << 2));

    for (int t = 1; t <= L_SEQ; ++t) {
      const int P = t & 1;
      const float c0 = tagc(t);
      // phase A: h0_t from prefetch (stale-read; validate + poll fallback)
      pf_wait0(pfA);
      float4 a = pf_finish(pfA, h0s + (t & RM) * H_DIM + (tid << 2), c0);
      lds4[P][tid + (tid >> 3)] = a;
      if (t < L_SEQ)   // next h0 prefetch; drained by later vmcnt(0)s
        pf_issue(pfA, h0s + ((t + 1) & RM) * H_DIM + (tid << 2));
      __syncthreads();
      float pa = 0.f, pb = 0.f;
      #pragma unroll
      for (int k = 0; k < 8; ++k) {      // ih dot over lane's 8 f4 of h0_t
        float4 h = lds4[P][9 * lane + k];
        pa += dot4(wihr[k], h);
        pb += dot4(wihr[8 + k], h);
      }
      // phase B: h1_{t-1} fresh detect -- wide-poll by half the WG, late position
      const float c1 = tagc(t - 1);
      if (tid < 256) {
        float4 u, v;
        poll8(h1s + ((t - 1) & RM) * H_DIM + (tid << 3), c1, u, v);
        const int j0 = 2 * tid, j1 = 2 * tid + 1;
        lds4[P][576 + j0 + (j0 >> 3)] = u;
        lds4[P][576 + j1 + (j1 >> 3)] = v;
      }
      __syncthreads();
      #pragma unroll
      for (int k = 0; k < 8; ++k) {      // hh dot over lane's 8 f4 of h1_{t-1}
        float4 h = lds4[P][576 + 9 * lane + k];
        pa += dot4(whhr[k], h);
        pb += dot4(whhr[8 + k], h);
      }
      #pragma unroll
      for (int m = 1; m < 64; m <<= 1) { // 64-lane reduce, 2 parallel chains
        pa += __shfl_xor(pa, m); pb += __shfl_xor(pb, m);
      }
      if (lane == 0) {                   // lane0 holds both rows: packed publish
        const float ct = tagc(t);
        cstore2f(h1s + (t & RM) * H_DIM + r0,
                 tanh_fast(pa + ba) + ct, tanh_fast(pb + bb) + ct);
      }
    }
  }
}

extern "C" void kernel_launch(void* const* d_in, const int* in_sizes, int n_in,
                              void* d_out, int out_size, void* d_ws, size_t ws_size,
                              hipStream_t stream) {
  const float* xx   = (const float*)d_in[0];
  const float* Wih0 = (const float*)d_in[1];
  const float* Whh0 = (const float*)d_in[2];
  const float* bih0 = (const float*)d_in[3];
  const float* bhh0 = (const float*)d_in[4];
  const float* Wih1 = (const float*)d_in[5];
  const float* Whh1 = (const float*)d_in[6];
  const float* bih1 = (const float*)d_in[7];
  const float* bhh1 = (const float*)d_in[8];
  const float* Wfc  = (const float*)d_in[9];
  const float* bfc  = (const float*)d_in[10];

  unsigned* runctr = (unsigned*)d_ws;
  unsigned* bslots = (unsigned*)((char*)d_ws + 256);
  float* h0s       = (float*)((char*)d_ws + 4096);
  float* h1s       = (float*)((char*)d_ws + 4096 + RD * H_DIM * sizeof(float));

  rnn2_widepoll<<<dim3(NWG), dim3(TPB), 0, stream>>>(
      xx, Wih0, Whh0, bih0, bhh0, Wih1, Whh1, bih1, bhh1, Wfc, bfc,
      (float*)d_out, runctr, bslots, h0s, h1s);
}